// Round 12
// baseline (49.316 us; speedup 1.0000x reference)
//
#include <hip/hip_runtime.h>
#include <hip/hip_bf16.h>

// MMD loss, MI355X. Round 12 (R11 + nontemporal-store type fix):
//  Evidence R3-R10: gram bound by instruction/issue count + per-block
//  overhead (warm replays: 0 HBM, idle pipes, same time). Cut instructions:
//  (1) fragment-PAIR layout: one dwordx4/lane covers two K-steps -> 32
//      loads/wave (was 64);
//  (2) 4 tiles per block, no intra-loop barriers -> 1/4 prologue/epilogue/
//      launch overhead, A-band reuse across consecutive tiles;
//  (3) prep: block per 16-row group, LDS transpose, single coalesced 16B
//      store/thread (kills scattered 8B RMW stores).
//  Carried: fp8 e4m3, skip-exp epilogue + analytic diagonal, symmetry,
//  no atomics, XCD-chunked bijective swizzle, block partials + reduce.
//
// ws layout: [sfb fp8 fragpair | tfb fp8 fragpair | x2s | x2t | wv | bout]

typedef float f32x4 __attribute__((ext_vector_type(4)));
typedef long long2v __attribute__((ext_vector_type(2)));
typedef unsigned int u32x4 __attribute__((ext_vector_type(4)));

#define D 256  // feature dim

// f32 -> OCP e4m3fn, RNE, FTZ on subnormals (|x|<2^-6 -> 0; harmless here).
static __device__ __forceinline__ unsigned int f32_to_e4m3(float f) {
    unsigned int u = __float_as_uint(f);
    unsigned int sg = (u >> 24) & 0x80;
    unsigned int um = u & 0x7FFFFFFF;
    unsigned int r = um + 0x0007FFFF + ((um >> 20) & 1);  // RNE at 3 mant bits
    int e8 = (int)((r >> 23) & 0xFF) - 127 + 7;
    unsigned int m8 = (r >> 20) & 7;
    if (e8 <= 0) return sg;                                // flush to zero
    if (e8 > 15 || (e8 == 15 && m8 == 7)) return sg | 0x7E;  // clamp to 448
    return sg | ((unsigned)e8 << 3) | m8;
}

// Fragment-PAIR layout: row-group g (16 rows) x superstep ss (64 k) = 1024B
// unit at g*4096 + ss*1024. Lane l's 16B at +l*16: bytes0-7 = K-step 2ss
// (row l&15, k = 2ss*32 + (l>>4)*8 + j), bytes8-15 = K-step 2ss+1.

// One block per 16-row group: load 16x256 f32 coalesced, convert, LDS
// transpose to fragpair order, one coalesced 16B store per thread.
__global__ __launch_bounds__(256) void prep_kernel(
    const float* __restrict__ sf, const float* __restrict__ tf,
    const int* __restrict__ lbl, const float* __restrict__ cw,
    unsigned char* __restrict__ sfb, unsigned char* __restrict__ tfb,
    float* __restrict__ x2s, float* __restrict__ x2t,
    float* __restrict__ wv, int ns)
{
    __shared__ unsigned int ldsb[1024];  // 4096 B staging

    int gb = blockIdx.x;
    int nsg = ns >> 4;
    bool is_src = gb < nsg;
    int gloc = is_src ? gb : gb - nsg;
    const float* src = (is_src ? sf : tf) + (size_t)gloc * 16 * D;
    unsigned char* dstb = (is_src ? sfb : tfb) + (size_t)gloc * 4096;

    int tid = threadIdx.x;
    int l = tid & 63;
    int w = tid >> 6;

    if (is_src && tid < 16) {
        int r = gloc * 16 + tid;
        wv[r] = cw[lbl[r]];
    }

    #pragma unroll
    for (int p = 0; p < 4; ++p) {
        int row = 4 * p + w;             // local row 0..15
        int k0 = l * 4;                  // 4 consecutive k per thread
        float4 v = *(const float4*)(src + row * D + k0);
        unsigned int packed = f32_to_e4m3(v.x)
                            | (f32_to_e4m3(v.y) << 8)
                            | (f32_to_e4m3(v.z) << 16)
                            | (f32_to_e4m3(v.w) << 24);
        int s  = k0 >> 5;
        int kg = (k0 >> 3) & 3;
        int off = (s >> 1) * 1024 + (row + 16 * kg) * 16 + (s & 1) * 8 + (k0 & 7);
        ldsb[off >> 2] = packed;

        float ps = v.x * v.x + v.y * v.y + v.z * v.z + v.w * v.w;
        #pragma unroll
        for (int o = 32; o; o >>= 1) ps += __shfl_xor(ps, o);
        if (l == 0) {
            int gr = gloc * 16 + row;
            if (is_src) x2s[gr] = ps; else x2t[gr] = ps;
        }
    }
    __syncthreads();
    u32x4 val = ((const u32x4*)ldsb)[tid];
    __builtin_nontemporal_store(val, ((u32x4*)dstb) + tid);
}

// Decode flat tile id -> mode/bi/bj/pointers (block-uniform scalar work).
static __device__ __forceinline__ void decode_tile(
    int blk, int ti_s, int ti_t,
    const unsigned char* sfb, const unsigned char* tfb,
    const float* x2s, const float* x2t,
    int& mode, int& bi, int& bj,
    const unsigned char*& X, const unsigned char*& Y,
    const float*& x2x, const float*& x2y, float& factor)
{
    int tri_s = ti_s * (ti_s + 1) / 2;
    int tri_t = ti_t * (ti_t + 1) / 2;
    if (blk < tri_s + tri_t) {
        int T, idx;
        if (blk < tri_s) { mode = 0; idx = blk; T = ti_s; X = sfb; Y = sfb; x2x = x2s; x2y = x2s; }
        else { mode = 1; idx = blk - tri_s; T = ti_t; X = tfb; Y = tfb; x2x = x2t; x2y = x2t; }
        bi = (int)((2.0f * T + 1.0f -
                    sqrtf((float)((2 * T + 1) * (2 * T + 1) - 8 * idx))) * 0.5f);
        if (bi < 0) bi = 0;
        if (bi > T - 1) bi = T - 1;
        int base = bi * (2 * T - bi + 1) / 2;
        while (base > idx) { --bi; base = bi * (2 * T - bi + 1) / 2; }
        while (idx >= base + (T - bi)) { base += (T - bi); ++bi; }
        bj = bi + (idx - base);
    } else {
        int idx = blk - tri_s - tri_t;
        mode = 2; bi = idx / ti_t; bj = idx % ti_t;
        X = sfb; Y = tfb; x2x = x2s; x2y = x2t;
    }
    factor = (mode != 2 && bi != bj) ? 2.0f : 1.0f;
}

// Fused gram kernel, TPB tiles per block, no intra-loop barriers.
// Block 256 thr = 4 waves (2x2), tile 128x128, wave tile 64x64.
__global__ __launch_bounds__(256, 3) void gram_kernel(
    const unsigned char* __restrict__ sfb, const unsigned char* __restrict__ tfb,
    const float* __restrict__ x2s, const float* __restrict__ x2t,
    const float* __restrict__ wv, float* __restrict__ bout,
    int ti_s, int ti_t, int NT, int NB, int TPB)
{
    // Bijective XCD-chunked swizzle: same-XCD blocks -> contiguous tiles.
    int orig = blockIdx.x;
    int q = NB >> 3, rm = NB & 7, xcd = orig & 7, of = orig >> 3;
    int lb = (xcd < rm ? xcd * (q + 1) : rm * (q + 1) + (xcd - rm) * q) + of;
    int tbeg = lb * TPB;
    int tend = min(tbeg + TPB, NT);

    int wid = threadIdx.x >> 6;
    int lane = threadIdx.x & 63;
    int wr = wid >> 1, wc = wid & 1;
    int crow = (lane >> 4) * 4;
    int ccol = lane & 15;

    float s0 = 0.0f, s1 = 0.0f, s2 = 0.0f;

    for (int t = tbeg; t < tend; ++t) {
        int mode, bi, bj; float factor;
        const unsigned char *X, *Y; const float *x2xp, *x2yp;
        decode_tile(t, ti_s, ti_t, sfb, tfb, x2s, x2t,
                    mode, bi, bj, X, Y, x2xp, x2yp, factor);

        int R0 = bi * 128 + wr * 64;
        int C0 = bj * 128 + wc * 64;
        const unsigned char* XA = X + (size_t)(R0 >> 4) * 4096 + lane * 16;
        const unsigned char* YB = Y + (size_t)(C0 >> 4) * 4096 + lane * 16;

        f32x4 acc[4][4] = {};
        long2v a2[2][4], b2[2][4];
        #pragma unroll
        for (int m = 0; m < 4; ++m) {
            a2[0][m] = *(const long2v*)(XA + m * 4096);
            b2[0][m] = *(const long2v*)(YB + m * 4096);
        }
        #pragma unroll
        for (int ss = 0; ss < 4; ++ss) {
            const int cur = ss & 1;
            if (ss < 3) {
                #pragma unroll
                for (int m = 0; m < 4; ++m) {
                    a2[cur ^ 1][m] = *(const long2v*)(XA + m * 4096 + (ss + 1) * 1024);
                    b2[cur ^ 1][m] = *(const long2v*)(YB + m * 4096 + (ss + 1) * 1024);
                }
            }
            #pragma unroll
            for (int m = 0; m < 4; ++m)
                #pragma unroll
                for (int n = 0; n < 4; ++n)
                    acc[m][n] = __builtin_amdgcn_mfma_f32_16x16x32_fp8_fp8(
                        a2[cur][m][0], b2[cur][n][0], acc[m][n], 0, 0, 0);
            #pragma unroll
            for (int m = 0; m < 4; ++m)
                #pragma unroll
                for (int n = 0; n < 4; ++n)
                    acc[m][n] = __builtin_amdgcn_mfma_f32_16x16x32_fp8_fp8(
                        a2[cur][m][1], b2[cur][n][1], acc[m][n], 0, 0, 0);
        }

        // Skip-exp epilogue: all sq>=180 -> K underflows f32 -> contributes 0.
        float x2yc[4];
        #pragma unroll
        for (int n = 0; n < 4; ++n) x2yc[n] = x2yp[C0 + 16 * n + ccol];

        float s = 0.0f;
        #pragma unroll
        for (int m = 0; m < 4; ++m) {
            #pragma unroll
            for (int r = 0; r < 4; ++r) {
                int gr = R0 + 16 * m + crow + r;
                float rx2 = x2xp[gr];
                float sq0 = fmaxf(rx2 + x2yc[0] - 2.0f * acc[m][0][r], 0.0f);
                float sq1 = fmaxf(rx2 + x2yc[1] - 2.0f * acc[m][1][r], 0.0f);
                float sq2 = fmaxf(rx2 + x2yc[2] - 2.0f * acc[m][2][r], 0.0f);
                float sq3 = fmaxf(rx2 + x2yc[3] - 2.0f * acc[m][3][r], 0.0f);
                float mn = fminf(fminf(sq0, sq1), fminf(sq2, sq3));
                if (__any(mn < 180.0f)) {   // rare: near-duplicate rows only
                    float rw = (mode != 1) ? wv[gr] : 1.0f;
                    float sqv[4] = {sq0, sq1, sq2, sq3};
                    #pragma unroll
                    for (int n = 0; n < 4; ++n) {
                        int gc = C0 + 16 * n + ccol;
                        float K = __expf(-0.5f * sqv[n]);
                        if (mode != 2 && gr == gc) K = 0.0f;  // diag in reduce
                        float wf = (mode == 0) ? rw * wv[gc] : rw;
                        s += wf * K;
                    }
                }
            }
        }
        s *= factor;
        if (mode == 0) s0 += s; else if (mode == 1) s1 += s; else s2 += s;
    }

    #pragma unroll
    for (int o = 32; o; o >>= 1) {
        s0 += __shfl_xor(s0, o);
        s1 += __shfl_xor(s1, o);
        s2 += __shfl_xor(s2, o);
    }
    __shared__ float bsum[4][3];
    if (lane == 0) { bsum[wid][0] = s0; bsum[wid][1] = s1; bsum[wid][2] = s2; }
    __syncthreads();
    if (threadIdx.x < 3) {
        float v = bsum[0][threadIdx.x] + bsum[1][threadIdx.x]
                + bsum[2][threadIdx.x] + bsum[3][threadIdx.x];
        bout[orig * 3 + threadIdx.x] = v;
    }
}

// Single-block final reduce: n = sum(wv), dsq = sum(wv^2) (analytic Kss
// diag), Ktt diag = nt, three mode sums from bout, combine.
__global__ __launch_bounds__(1024) void reduce_kernel(
    const float* __restrict__ wv, int ns,
    const float* __restrict__ bout, int NB,
    float* __restrict__ out, int nt)
{
    int tid = threadIdx.x;
    float n = 0.0f, dsq = 0.0f, a0 = 0.0f, a1 = 0.0f, a2 = 0.0f;
    for (int i = tid; i < ns; i += 1024) {
        float w = wv[i];
        n += w;
        dsq += w * w;
    }
    for (int i = tid; i < NB; i += 1024) {
        a0 += bout[i * 3 + 0];
        a1 += bout[i * 3 + 1];
        a2 += bout[i * 3 + 2];
    }
    #pragma unroll
    for (int o = 32; o; o >>= 1) {
        n   += __shfl_xor(n, o);
        dsq += __shfl_xor(dsq, o);
        a0  += __shfl_xor(a0, o);
        a1  += __shfl_xor(a1, o);
        a2  += __shfl_xor(a2, o);
    }
    __shared__ float ln[16], ld[16], l0[16], l1[16], l2[16];
    int w = tid >> 6;
    if ((tid & 63) == 0) { ln[w] = n; ld[w] = dsq; l0[w] = a0; l1[w] = a1; l2[w] = a2; }
    __syncthreads();
    if (tid == 0) {
        float N = 0, DQ = 0, A0 = 0, A1 = 0, A2 = 0;
        #pragma unroll
        for (int i = 0; i < 16; ++i) {
            N += ln[i]; DQ += ld[i]; A0 += l0[i]; A1 += l1[i]; A2 += l2[i];
        }
        float fnt = (float)nt;
        out[0] = (A0 + DQ) / (N * N) + (A1 + fnt) / (fnt * fnt)
               - 2.0f * A2 / (N * fnt);
    }
}

extern "C" void kernel_launch(void* const* d_in, const int* in_sizes, int n_in,
                              void* d_out, int out_size, void* d_ws, size_t ws_size,
                              hipStream_t stream) {
    const float* sf = (const float*)d_in[0];
    const int* lbl = (const int*)d_in[1];
    const float* tf = (const float*)d_in[2];
    const float* cw = (const float*)d_in[3];
    float* out = (float*)d_out;

    int ns = in_sizes[1];
    int d = in_sizes[0] / ns;   // expect 256
    int nt = in_sizes[2] / d;

    char* p = (char*)d_ws;
    unsigned char* sfb = (unsigned char*)p;  p += (size_t)ns * d;
    unsigned char* tfb = (unsigned char*)p;  p += (size_t)nt * d;
    float* x2s = (float*)p;                  p += (size_t)ns * sizeof(float);
    float* x2t = (float*)p;                  p += (size_t)nt * sizeof(float);
    float* wv  = (float*)p;                  p += (size_t)ns * sizeof(float);
    float* bout = (float*)p;

    prep_kernel<<<(ns + nt) / 16, 256, 0, stream>>>(sf, tf, lbl, cw, sfb, tfb,
                                                    x2s, x2t, wv, ns);

    int ti_s = ns / 128, ti_t = nt / 128;
    int tri_s = ti_s * (ti_s + 1) / 2;
    int tri_t = ti_t * (ti_t + 1) / 2;
    int NT = tri_s + tri_t + ti_s * ti_t;   // 2080
    int TPB = 4;
    int NB = (NT + TPB - 1) / TPB;          // 520
    gram_kernel<<<NB, 256, 0, stream>>>(sfb, tfb, x2s, x2t, wv, bout,
                                        ti_s, ti_t, NT, NB, TPB);

    reduce_kernel<<<1, 1024, 0, stream>>>(wv, ns, bout, NB, out, nt);
}